// Round 1
// baseline (192.334 us; speedup 1.0000x reference)
//
#include <hip/hip_runtime.h>
#include <math.h>

#define EPS_N 1e-12f
#define MARGIN 0.3f
#define INF_BITS 0x7f800000u
#define NCLS 128     // label space (randint(0,128))
#define D 512
#define PADR 256     // padded rows after fh so banded staging can over-read safely

typedef __attribute__((ext_vector_type(8))) short short8;   // 8 bf16 = 4 VGPRs
typedef __attribute__((ext_vector_type(4))) float float4v;  // MFMA 16x16 accum

__device__ __forceinline__ unsigned short f2bf(float f) {   // RNE bf16
    unsigned u = __float_as_uint(f);
    u += 0x7fff + ((u >> 16) & 1);
    return (unsigned short)(u >> 16);
}
__device__ __forceinline__ void gl16(const void* g, void* l) {
    // 16B async global->LDS; global addr per-lane, LDS dest = uniform base + lane*16
    __builtin_amdgcn_global_load_lds((const __attribute__((address_space(1))) void*)g,
                                     (__attribute__((address_space(3))) void*)l, 16, 0, 0);
}

// ---------------------------------------------------------------------------
// K0: one-block bucketing, coalesced-metadata (unchanged).
// ---------------------------------------------------------------------------
__global__ __launch_bounds__(1024) void k_bucket(const int* __restrict__ lab, int Bn,
        int* __restrict__ pos, int* __restrict__ labp,
        int* __restrict__ cstart_g, int* __restrict__ ccnt_g,
        float* __restrict__ meanpos, float* __restrict__ pcinv,
        int* __restrict__ poscnt, unsigned* __restrict__ minbits) {
    __shared__ int cnt[NCLS], cs[NCLS + 1], off[NCLS], sa[NCLS], sb[NCLS];
    int tid = threadIdx.x;
    if (tid < NCLS) cnt[tid] = 0;
    __syncthreads();
    for (int i = tid; i < Bn; i += 1024) atomicAdd(&cnt[lab[i] & (NCLS - 1)], 1);
    __syncthreads();
    if (tid < NCLS) sa[tid] = cnt[tid];
    __syncthreads();
    int* src = sa; int* dst = sb;
    for (int ofs = 1; ofs < NCLS; ofs <<= 1) {          // Hillis-Steele inclusive
        if (tid < NCLS) dst[tid] = src[tid] + ((tid >= ofs) ? src[tid - ofs] : 0);
        __syncthreads();
        int* t = src; src = dst; dst = t;
    }
    if (tid < NCLS) {
        int ex = src[tid] - cnt[tid];                   // exclusive
        cs[tid] = ex;
        off[tid] = ex;
        cstart_g[tid] = ex;
        ccnt_g[tid] = cnt[tid];
    }
    if (tid == 0) cs[NCLS] = Bn;
    __syncthreads();
    // coalesced per-slot metadata: class(p) = largest l with cs[l] <= p
    for (int p = tid; p < Bn; p += 1024) {
        int lo = 0, hi = NCLS - 1;
        #pragma unroll
        for (int s = 0; s < 7; ++s) {
            int mid = (lo + hi + 1) >> 1;
            if (cs[mid] <= p) lo = mid; else hi = mid - 1;
        }
        int l = lo, m = cnt[l];
        labp[p] = l;
        poscnt[p] = m;
        pcinv[p] = 1.0f / (float)m;
        meanpos[p] = 0.f;          // accumulates raw dist-sums (posband3)
        minbits[p] = INF_BITS;
    }
    // pos scatter (reads coalesced; only pos[] store is scattered-by-class)
    for (int i = tid; i < Bn; i += 1024) {
        int l = lab[i] & (NCLS - 1);
        pos[i] = atomicAdd(&off[l], 1);
    }
}

// ---------------------------------------------------------------------------
// K1: normalize; one wave per row, no __syncthreads (unchanged).
// ---------------------------------------------------------------------------
__global__ __launch_bounds__(256) void k_normalize(const float* __restrict__ x,
        const int* __restrict__ pos, unsigned short* __restrict__ fh,
        float* __restrict__ sqp) {
    int w = threadIdx.x >> 6, L = threadIdx.x & 63;
    int row = blockIdx.x * 4 + w;
    const float* xr = x + (size_t)row * D + L * 8;
    float4 a = *(const float4*)xr;
    float4 b = *(const float4*)(xr + 4);
    float ss = a.x * a.x;
    ss = fmaf(a.y, a.y, ss); ss = fmaf(a.z, a.z, ss); ss = fmaf(a.w, a.w, ss);
    ss = fmaf(b.x, b.x, ss); ss = fmaf(b.y, b.y, ss);
    ss = fmaf(b.z, b.z, ss); ss = fmaf(b.w, b.w, ss);
    #pragma unroll
    for (int off = 32; off; off >>= 1) ss += __shfl_xor(ss, off, 64);
    float inv = 1.0f / fmaxf(sqrtf(ss), EPS_N);
    int prow = pos[row];
    if (L == 0) sqp[prow] = ss * inv * inv;
    ushort4 h0, h1;
    h0.x = f2bf(a.x * inv); h0.y = f2bf(a.y * inv);
    h0.z = f2bf(a.z * inv); h0.w = f2bf(a.w * inv);
    h1.x = f2bf(b.x * inv); h1.y = f2bf(b.y * inv);
    h1.z = f2bf(b.z * inv); h1.w = f2bf(b.w * inv);
    unsigned short* dst = fh + (size_t)prow * D + L * 8;
    *(ushort4*)dst = h0;
    *(ushort4*)(dst + 4) = h1;
}

// ---------------------------------------------------------------------------
// K2: banded positive stats v3 (unchanged).
// ---------------------------------------------------------------------------
__global__ __launch_bounds__(256) void k_posband3(
    const unsigned short* __restrict__ fh, const float* __restrict__ sqp,
    const int* __restrict__ labp, const int* __restrict__ cstart_g,
    const int* __restrict__ ccnt_g, float* __restrict__ meanpos, int Bn)
{
    __shared__ unsigned short SA[16 * 128];    // 4 KB per K-chunk
    __shared__ unsigned short SB[128 * 128];   // 32 KB per K-chunk
    __shared__ float sqr[16], rs[16];
    __shared__ int labr[16];
    __shared__ float sqc[128];
    __shared__ int labc[128];

    const int r0 = blockIdx.x * 16;
    const int tid = threadIdx.x, w = tid >> 6, L = tid & 63;
    const int lm = L & 15, ls = L >> 4;
    const int srow = L >> 4;      // 0..3 rows per gl16 group
    const int sseg = L & 15;      // 16-B seg slot within a 256 B row

    if (tid < 16) {
        labr[tid] = labp[r0 + tid];
        sqr[tid]  = sqp[r0 + tid];
        rs[tid]   = 0.f;
    }
    __syncthreads();
    const int c0 = cstart_g[labr[0]];
    const int c1 = cstart_g[labr[15]] + ccnt_g[labr[15]];

    for (int cc0 = c0; cc0 < c1; cc0 += 128) {
        __syncthreads();
        if (tid < 128) {
            int q = cc0 + tid;
            if (q < Bn) { sqc[tid] = sqp[q]; labc[tid] = labp[q]; }
            else        { sqc[tid] = 0.f;    labc[tid] = -1; }
        }
        float4v acc[2];
        acc[0] = (float4v){0.f, 0.f, 0.f, 0.f};
        acc[1] = (float4v){0.f, 0.f, 0.f, 0.f};

        for (int k0 = 0; k0 < D; k0 += 128) {
            __syncthreads();
            {   // SA: wave w stages rows w*4 .. w*4+3 (one gl16)
                int rmat = w * 4 + srow;
                int seg = sseg ^ (rmat & 15);
                gl16(fh + (size_t)(r0 + rmat) * D + k0 + seg * 8, &SA[(w * 4) * 128]);
            }
            #pragma unroll
            for (int it = 0; it < 8; ++it) {  // SB: 32 gl16 across 4 waves
                int rmat = it * 16 + w * 4 + srow;          // 0..127 (may over-read pad)
                int seg = sseg ^ (rmat & 15);
                gl16(fh + (size_t)(cc0 + rmat) * D + k0 + seg * 8,
                     &SB[(size_t)(it * 16 + w * 4) * 128]);
            }
            __syncthreads();
            #pragma unroll
            for (int h = 0; h < 4; ++h) {      // K=128 in 4 MFMA sub-steps
                int ra = lm;
                short8 af = *(const short8*)&SA[ra * 128 + (((h * 4 + ls) ^ (ra & 15))) * 8];
                #pragma unroll
                for (int ct = 0; ct < 2; ++ct) {
                    int rb = w * 32 + ct * 16 + lm;
                    short8 bf = *(const short8*)&SB[rb * 128 + (((h * 4 + ls) ^ (rb & 15))) * 8];
                    acc[ct] = __builtin_amdgcn_mfma_f32_16x16x32_bf16(af, bf, acc[ct], 0, 0, 0);
                }
            }
        }
        // epilogue: masked dist row-sums. C/D: row = ls*4+v, col = w*32+ct*16+lm
        #pragma unroll
        for (int v = 0; v < 4; ++v) {
            int ri = ls * 4 + v;
            int p = r0 + ri;
            int lr = labr[ri];
            float sr = sqr[ri];
            float sum = 0.f;
            #pragma unroll
            for (int ct = 0; ct < 2; ++ct) {
                int ci = w * 32 + ct * 16 + lm;
                int q = cc0 + ci;
                float d2 = sr + sqc[ci] - 2.0f * acc[ct][v];
                float dd = (d2 > 0.f) ? sqrtf(d2) : 0.f;
                sum += ((labc[ci] == lr) && (q != p)) ? dd : 0.f;
            }
            #pragma unroll
            for (int off = 8; off; off >>= 1) sum += __shfl_xor(sum, off, 64);
            if (lm == 0) atomicAdd(&rs[ri], sum);
        }
    }
    __syncthreads();
    if (tid < 16 && rs[tid] != 0.f) atomicAdd(&meanpos[r0 + tid], rs[tid]);
}

// ---------------------------------------------------------------------------
// K3 (R12 rewrite): 256x128-tile, BK=32, double-buffered "minimum 2-phase"
// pipeline (T3 recipe): issue next tile's global_load_lds BEFORE ds_read+MFMA
// of the current tile, single drain+barrier per K-tile. 4 waves x (64x128)
// per block -> 12 ds_read_b128 : 32 MFMA per wave per K-tile (vs 16:32 at
// 128^2), ~238 regs -> 8 waves/CU -> 2 blocks/CU so drains/epilogue of one
// block overlap the other's MFMA. Grid = sum_I (2I+2) = 1056 blocks covering
// every unordered pair >=1x via idempotent row-side + col-side atomicMin.
// XCD-bijective swizzle (1056 % 8 == 0). Epilogue specialized on class-range
// overlap (sorted labels -> ~6% of blocks need the label compare).
// ---------------------------------------------------------------------------
#define BK 32
#define NKT (D / BK)    // 16 K-tiles

template<bool OVL>
__device__ __forceinline__ void k3_epi(
    const float4v (&acc)[4][8], int i0, int j0, int w, int lm, int ls,
    const float* s_mp2r, const float* s_sqr, const int* s_labr,
    const float* s_mp2c, const float* s_sqc, const int* s_labc,
    unsigned* __restrict__ minbits)
{
    const float INFF = __uint_as_float(INF_BITS);
    float sc[8], mp2c[8]; int lc[8];
    #pragma unroll
    for (int ni = 0; ni < 8; ++ni) {
        int cl = ni * 16 + lm;
        sc[ni]   = s_sqc[cl];
        mp2c[ni] = s_mp2c[cl];
        lc[ni]   = OVL ? s_labc[cl] : 0;
    }
    float vminc[8];
    #pragma unroll
    for (int ni = 0; ni < 8; ++ni) vminc[ni] = INFF;

    #pragma unroll
    for (int mi = 0; mi < 4; ++mi) {
        #pragma unroll
        for (int v = 0; v < 4; ++v) {
            int rl = w * 64 + mi * 16 + ls * 4 + v;
            float mp2r = s_mp2r[rl];
            float sr   = s_sqr[rl];
            int   li   = OVL ? s_labr[rl] : 0;
            float vminr = INFF;
            #pragma unroll
            for (int ni = 0; ni < 8; ++ni) {
                float d2 = fmaf(-2.0f, acc[mi][ni][v], sr + sc[ni]);
                bool neq = OVL ? (li != lc[ni]) : true;
                vminr     = fminf(vminr,     (neq && d2 > mp2r)      ? d2 : INFF);
                vminc[ni] = fminf(vminc[ni], (neq && d2 > mp2c[ni])  ? d2 : INFF);
            }
            #pragma unroll
            for (int off = 8; off; off >>= 1)
                vminr = fminf(vminr, __shfl_xor(vminr, off, 64));
            if (lm == 0 && __float_as_uint(vminr) != INF_BITS)
                atomicMin(&minbits[i0 + rl], __float_as_uint(vminr));
        }
    }
    #pragma unroll
    for (int ni = 0; ni < 8; ++ni) {
        float vc = vminc[ni];
        vc = fminf(vc, __shfl_xor(vc, 16, 64));
        vc = fminf(vc, __shfl_xor(vc, 32, 64));
        if (ls == 0 && __float_as_uint(vc) != INF_BITS)
            atomicMin(&minbits[j0 + ni * 16 + lm], __float_as_uint(vc));
    }
}

__global__ __launch_bounds__(256, 2) void k_minsh_mfma(
    const unsigned short* __restrict__ fh, const float* __restrict__ sqp,
    const int* __restrict__ labp, const float* __restrict__ meanpos,
    const float* __restrict__ pcinv, unsigned* __restrict__ minbits)
{
    // --- XCD-bijective swizzle (m204) then triangular-band decode ---
    const int T = gridDim.x;
    const int bb = blockIdx.x;
    const int q8 = T >> 3, r8 = T & 7, xcd = bb & 7, lin = bb >> 3;
    int t = (xcd < r8 ? xcd * (q8 + 1) : r8 * (q8 + 1) + (xcd - r8) * q8) + lin;
    // blocks before row-tile I: C(I) = I*(I+1); row I has 2I+2 col-tiles
    int I = (int)((sqrtf(4.0f * (float)t + 1.0f) - 1.0f) * 0.5f);
    while ((I + 1) * (I + 2) <= t) ++I;
    while (I * (I + 1) > t) --I;
    const int J = t - I * (I + 1);
    const int i0 = I * 256;      // 256 output rows
    const int j0 = J * 128;      // 128 output cols (j0 <= i0+128)

    __shared__ unsigned short LA[2][384 * 32];   // [buf][(256 A + 128 B rows) * 32k] = 48 KB
    __shared__ float s_mp2r[256], s_sqr[256], s_mp2c[128], s_sqc[128];
    __shared__ int s_labr[256], s_labc[128];

    const int tid = threadIdx.x;
    const int w = tid >> 6, L = tid & 63;
    const int lm = L & 15, ls = L >> 4;

    // --- stage source pointers: pre-swizzled global so gl16's linear LDS
    // write + XOR-slot ds_read compose to identity (rule: both-sides swizzle)
    const unsigned short* srcA[4];
    #pragma unroll
    for (int qq = 0; qq < 4; ++qq) {
        int c = tid + 256 * qq;                   // A chunk 0..1023
        int r = c >> 2;
        int g = (c & 3) ^ ((r >> 1) & 3);
        srcA[qq] = fh + (size_t)(i0 + r) * D + g * 8;
    }
    const unsigned short* srcB[2];
    #pragma unroll
    for (int qq = 0; qq < 2; ++qq) {
        int c = tid + 256 * qq;                   // B chunk 0..511
        int r = c >> 2;
        int g = (c & 3) ^ ((r >> 1) & 3);
        srcB[qq] = fh + (size_t)(j0 + r) * D + g * 8;
    }

    #define K3_STAGE(kt, bsel)                                                  \
        do {                                                                    \
            const int kofs_ = (kt) * BK;                                        \
            unsigned short* ba_ = &LA[(bsel)][0];                               \
            _Pragma("unroll")                                                   \
            for (int qq = 0; qq < 4; ++qq)                                      \
                gl16(srcA[qq] + kofs_, ba_ + (w * 64 + 256 * qq) * 8);          \
            unsigned short* bb_ = &LA[(bsel)][256 * 32];                        \
            _Pragma("unroll")                                                   \
            for (int qq = 0; qq < 2; ++qq)                                      \
                gl16(srcB[qq] + kofs_, bb_ + (w * 64 + 256 * qq) * 8);          \
        } while (0)

    float4v acc[4][8];
    #pragma unroll
    for (int mi = 0; mi < 4; ++mi)
        #pragma unroll
        for (int ni = 0; ni < 8; ++ni) acc[mi][ni] = (float4v){0.f, 0.f, 0.f, 0.f};

    // --- prologue: stage tile 0 + metadata, full drain once ---
    K3_STAGE(0, 0);
    {
        int p = i0 + tid;
        float mp = meanpos[p] * pcinv[p];
        s_mp2r[tid] = mp * mp;
        s_sqr[tid]  = sqp[p];
        s_labr[tid] = labp[p];
        if (tid < 128) {
            int pq = j0 + tid;
            float mq = meanpos[pq] * pcinv[pq];
            s_mp2c[tid] = mq * mq;
            s_sqc[tid]  = sqp[pq];
            s_labc[tid] = labp[pq];
        }
    }
    __syncthreads();

    // --- main loop: stage(kt+1) in flight UNDER reads+MFMA of kt, then drain ---
    #pragma unroll 2
    for (int kt = 0; kt < NKT; ++kt) {
        const int cur = kt & 1;
        if (kt + 1 < NKT) K3_STAGE(kt + 1, cur ^ 1);

        const unsigned short* bufA = &LA[cur][0];
        const unsigned short* bufB = &LA[cur][256 * 32];
        short8 af[4], bf[8];
        #pragma unroll
        for (int mi = 0; mi < 4; ++mi) {
            int r = w * 64 + mi * 16 + lm;
            af[mi] = *(const short8*)&bufA[r * 32 + ((ls ^ ((r >> 1) & 3)) << 3)];
        }
        #pragma unroll
        for (int ni = 0; ni < 8; ++ni) {
            int rb = ni * 16 + lm;
            bf[ni] = *(const short8*)&bufB[rb * 32 + ((ls ^ ((rb >> 1) & 3)) << 3)];
        }
        #pragma unroll
        for (int ni = 0; ni < 8; ++ni)
            #pragma unroll
            for (int mi = 0; mi < 4; ++mi)
                acc[mi][ni] = __builtin_amdgcn_mfma_f32_16x16x32_bf16(af[mi], bf[ni], acc[mi][ni], 0, 0, 0);

        __syncthreads();   // vmcnt(0)+lgkmcnt(0)+barrier: tile kt+1 landed, buf[cur] free
    }
    #undef K3_STAGE

    // --- epilogue: d2-space dual-side semi-hard mins ---
    // C/D: row = w*64 + mi*16 + ls*4 + v, col = ni*16 + lm
    const bool ovl = (s_labc[0] <= s_labr[255]) && (s_labr[0] <= s_labc[127]);
    if (ovl)
        k3_epi<true >(acc, i0, j0, w, lm, ls, s_mp2r, s_sqr, s_labr, s_mp2c, s_sqc, s_labc, minbits);
    else
        k3_epi<false>(acc, i0, j0, w, lm, ls, s_mp2r, s_sqr, s_labr, s_mp2c, s_sqc, s_labc, minbits);
}

// ---------------------------------------------------------------------------
// K4: final reduction (unchanged).
// ---------------------------------------------------------------------------
__global__ __launch_bounds__(1024) void k_finish(const float* __restrict__ meanpos,
        const float* __restrict__ pcinv, const int* __restrict__ poscnt,
        const unsigned* __restrict__ minbits, float* __restrict__ out, int Bn) {
    float lsum = 0.f; int lcnt = 0;
    for (int i = threadIdx.x; i < Bn; i += 1024) {
        int pc = poscnt[i];
        bool valid = (pc > 1) && (pc < Bn);
        unsigned mb = minbits[i];
        if (valid && mb != INF_BITS) {
            float v = fmaf(meanpos[i], pcinv[i], MARGIN - sqrtf(__uint_as_float(mb)));
            lsum += (v > 0.f) ? v : 0.f;
            lcnt += 1;
        }
    }
    __shared__ float ssum[16]; __shared__ int scnt[16];
    int lane = threadIdx.x & 63, wid = threadIdx.x >> 6;
    #pragma unroll
    for (int off = 32; off; off >>= 1) {
        lsum += __shfl_down(lsum, off, 64);
        lcnt += __shfl_down(lcnt, off, 64);
    }
    if (lane == 0) { ssum[wid] = lsum; scnt[wid] = lcnt; }
    __syncthreads();
    if (threadIdx.x == 0) {
        float s = 0.f; int c = 0;
        #pragma unroll
        for (int q = 0; q < 16; ++q) { s += ssum[q]; c += scnt[q]; }
        out[0] = (c > 0) ? s / (float)c : 0.f;
    }
}

// ---------------------------------------------------------------------------
extern "C" void kernel_launch(void* const* d_in, const int* in_sizes, int n_in,
                              void* d_out, int out_size, void* d_ws, size_t ws_size,
                              hipStream_t stream) {
    const float* x = (const float*)d_in[0];
    const int* lab = (const int*)d_in[1];
    int Bn = in_sizes[1];                 // 8192; D fixed at 512

    size_t nd = (size_t)(Bn + PADR) * D;  // padded for banded over-read (K2)
    unsigned short* fh = (unsigned short*)d_ws;
    float* sqp        = (float*)(fh + nd);
    float* meanpos    = sqp + Bn;         // raw dist-sums
    float* pcinv      = meanpos + Bn;
    int* poscnt       = (int*)(pcinv + Bn);
    unsigned* minbits = (unsigned*)(poscnt + Bn);
    int* pos          = (int*)(minbits + Bn);
    int* labp         = pos + Bn;
    int* cstart_g     = labp + Bn;
    int* ccnt_g       = cstart_g + NCLS;

    k_bucket<<<1, 1024, 0, stream>>>(lab, Bn, pos, labp, cstart_g, ccnt_g,
                                     meanpos, pcinv, poscnt, minbits);
    k_normalize<<<Bn / 4, 256, 0, stream>>>(x, pos, fh, sqp);
    k_posband3<<<Bn / 16, 256, 0, stream>>>(fh, sqp, labp, cstart_g, ccnt_g,
                                            meanpos, Bn);
    int nbr = Bn / 256;                   // 32 row-tiles
    int T = nbr * nbr + nbr;              // sum_I (2I+2) = 1056
    k_minsh_mfma<<<T, 256, 0, stream>>>(fh, sqp, labp, meanpos, pcinv, minbits);
    k_finish<<<1, 1024, 0, stream>>>(meanpos, pcinv, poscnt, minbits,
                                     (float*)d_out, Bn);
}

// Round 2
// 173.253 us; speedup vs baseline: 1.1101x; 1.1101x over previous
//
#include <hip/hip_runtime.h>
#include <math.h>

#define EPS_N 1e-12f
#define MARGIN 0.3f
#define INF_BITS 0x7f800000u
#define NCLS 128     // label space (randint(0,128))
#define D 512
#define PADR 256     // padded rows after fh so banded staging can over-read safely

typedef __attribute__((ext_vector_type(8))) short short8;   // 8 bf16 = 4 VGPRs
typedef __attribute__((ext_vector_type(4))) float float4v;  // MFMA 16x16 accum

__device__ __forceinline__ unsigned short f2bf(float f) {   // RNE bf16
    unsigned u = __float_as_uint(f);
    u += 0x7fff + ((u >> 16) & 1);
    return (unsigned short)(u >> 16);
}
__device__ __forceinline__ void gl16(const void* g, void* l) {
    // 16B async global->LDS; global addr per-lane, LDS dest = uniform base + lane*16
    __builtin_amdgcn_global_load_lds((const __attribute__((address_space(1))) void*)g,
                                     (__attribute__((address_space(3))) void*)l, 16, 0, 0);
}

// ---------------------------------------------------------------------------
// K0: one-block bucketing, coalesced-metadata (unchanged).
// ---------------------------------------------------------------------------
__global__ __launch_bounds__(1024) void k_bucket(const int* __restrict__ lab, int Bn,
        int* __restrict__ pos, int* __restrict__ labp,
        int* __restrict__ cstart_g, int* __restrict__ ccnt_g,
        float* __restrict__ meanpos, float* __restrict__ pcinv,
        int* __restrict__ poscnt, unsigned* __restrict__ minbits) {
    __shared__ int cnt[NCLS], cs[NCLS + 1], off[NCLS], sa[NCLS], sb[NCLS];
    int tid = threadIdx.x;
    if (tid < NCLS) cnt[tid] = 0;
    __syncthreads();
    for (int i = tid; i < Bn; i += 1024) atomicAdd(&cnt[lab[i] & (NCLS - 1)], 1);
    __syncthreads();
    if (tid < NCLS) sa[tid] = cnt[tid];
    __syncthreads();
    int* src = sa; int* dst = sb;
    for (int ofs = 1; ofs < NCLS; ofs <<= 1) {          // Hillis-Steele inclusive
        if (tid < NCLS) dst[tid] = src[tid] + ((tid >= ofs) ? src[tid - ofs] : 0);
        __syncthreads();
        int* t = src; src = dst; dst = t;
    }
    if (tid < NCLS) {
        int ex = src[tid] - cnt[tid];                   // exclusive
        cs[tid] = ex;
        off[tid] = ex;
        cstart_g[tid] = ex;
        ccnt_g[tid] = cnt[tid];
    }
    if (tid == 0) cs[NCLS] = Bn;
    __syncthreads();
    // coalesced per-slot metadata: class(p) = largest l with cs[l] <= p
    for (int p = tid; p < Bn; p += 1024) {
        int lo = 0, hi = NCLS - 1;
        #pragma unroll
        for (int s = 0; s < 7; ++s) {
            int mid = (lo + hi + 1) >> 1;
            if (cs[mid] <= p) lo = mid; else hi = mid - 1;
        }
        int l = lo, m = cnt[l];
        labp[p] = l;
        poscnt[p] = m;
        pcinv[p] = 1.0f / (float)m;
        meanpos[p] = 0.f;          // accumulates raw dist-sums (posband3)
        minbits[p] = INF_BITS;
    }
    // pos scatter (reads coalesced; only pos[] store is scattered-by-class)
    for (int i = tid; i < Bn; i += 1024) {
        int l = lab[i] & (NCLS - 1);
        pos[i] = atomicAdd(&off[l], 1);
    }
}

// ---------------------------------------------------------------------------
// K1: normalize; one wave per row, no __syncthreads (unchanged).
// ---------------------------------------------------------------------------
__global__ __launch_bounds__(256) void k_normalize(const float* __restrict__ x,
        const int* __restrict__ pos, unsigned short* __restrict__ fh,
        float* __restrict__ sqp) {
    int w = threadIdx.x >> 6, L = threadIdx.x & 63;
    int row = blockIdx.x * 4 + w;
    const float* xr = x + (size_t)row * D + L * 8;
    float4 a = *(const float4*)xr;
    float4 b = *(const float4*)(xr + 4);
    float ss = a.x * a.x;
    ss = fmaf(a.y, a.y, ss); ss = fmaf(a.z, a.z, ss); ss = fmaf(a.w, a.w, ss);
    ss = fmaf(b.x, b.x, ss); ss = fmaf(b.y, b.y, ss);
    ss = fmaf(b.z, b.z, ss); ss = fmaf(b.w, b.w, ss);
    #pragma unroll
    for (int off = 32; off; off >>= 1) ss += __shfl_xor(ss, off, 64);
    float inv = 1.0f / fmaxf(sqrtf(ss), EPS_N);
    int prow = pos[row];
    if (L == 0) sqp[prow] = ss * inv * inv;
    ushort4 h0, h1;
    h0.x = f2bf(a.x * inv); h0.y = f2bf(a.y * inv);
    h0.z = f2bf(a.z * inv); h0.w = f2bf(a.w * inv);
    h1.x = f2bf(b.x * inv); h1.y = f2bf(b.y * inv);
    h1.z = f2bf(b.z * inv); h1.w = f2bf(b.w * inv);
    unsigned short* dst = fh + (size_t)prow * D + L * 8;
    *(ushort4*)dst = h0;
    *(ushort4*)(dst + 4) = h1;
}

// ---------------------------------------------------------------------------
// K2: banded positive stats v3 (unchanged).
// ---------------------------------------------------------------------------
__global__ __launch_bounds__(256) void k_posband3(
    const unsigned short* __restrict__ fh, const float* __restrict__ sqp,
    const int* __restrict__ labp, const int* __restrict__ cstart_g,
    const int* __restrict__ ccnt_g, float* __restrict__ meanpos, int Bn)
{
    __shared__ unsigned short SA[16 * 128];    // 4 KB per K-chunk
    __shared__ unsigned short SB[128 * 128];   // 32 KB per K-chunk
    __shared__ float sqr[16], rs[16];
    __shared__ int labr[16];
    __shared__ float sqc[128];
    __shared__ int labc[128];

    const int r0 = blockIdx.x * 16;
    const int tid = threadIdx.x, w = tid >> 6, L = tid & 63;
    const int lm = L & 15, ls = L >> 4;
    const int srow = L >> 4;      // 0..3 rows per gl16 group
    const int sseg = L & 15;      // 16-B seg slot within a 256 B row

    if (tid < 16) {
        labr[tid] = labp[r0 + tid];
        sqr[tid]  = sqp[r0 + tid];
        rs[tid]   = 0.f;
    }
    __syncthreads();
    const int c0 = cstart_g[labr[0]];
    const int c1 = cstart_g[labr[15]] + ccnt_g[labr[15]];

    for (int cc0 = c0; cc0 < c1; cc0 += 128) {
        __syncthreads();
        if (tid < 128) {
            int q = cc0 + tid;
            if (q < Bn) { sqc[tid] = sqp[q]; labc[tid] = labp[q]; }
            else        { sqc[tid] = 0.f;    labc[tid] = -1; }
        }
        float4v acc[2];
        acc[0] = (float4v){0.f, 0.f, 0.f, 0.f};
        acc[1] = (float4v){0.f, 0.f, 0.f, 0.f};

        for (int k0 = 0; k0 < D; k0 += 128) {
            __syncthreads();
            {   // SA: wave w stages rows w*4 .. w*4+3 (one gl16)
                int rmat = w * 4 + srow;
                int seg = sseg ^ (rmat & 15);
                gl16(fh + (size_t)(r0 + rmat) * D + k0 + seg * 8, &SA[(w * 4) * 128]);
            }
            #pragma unroll
            for (int it = 0; it < 8; ++it) {  // SB: 32 gl16 across 4 waves
                int rmat = it * 16 + w * 4 + srow;          // 0..127 (may over-read pad)
                int seg = sseg ^ (rmat & 15);
                gl16(fh + (size_t)(cc0 + rmat) * D + k0 + seg * 8,
                     &SB[(size_t)(it * 16 + w * 4) * 128]);
            }
            __syncthreads();
            #pragma unroll
            for (int h = 0; h < 4; ++h) {      // K=128 in 4 MFMA sub-steps
                int ra = lm;
                short8 af = *(const short8*)&SA[ra * 128 + (((h * 4 + ls) ^ (ra & 15))) * 8];
                #pragma unroll
                for (int ct = 0; ct < 2; ++ct) {
                    int rb = w * 32 + ct * 16 + lm;
                    short8 bf = *(const short8*)&SB[rb * 128 + (((h * 4 + ls) ^ (rb & 15))) * 8];
                    acc[ct] = __builtin_amdgcn_mfma_f32_16x16x32_bf16(af, bf, acc[ct], 0, 0, 0);
                }
            }
        }
        // epilogue: masked dist row-sums. C/D: row = ls*4+v, col = w*32+ct*16+lm
        #pragma unroll
        for (int v = 0; v < 4; ++v) {
            int ri = ls * 4 + v;
            int p = r0 + ri;
            int lr = labr[ri];
            float sr = sqr[ri];
            float sum = 0.f;
            #pragma unroll
            for (int ct = 0; ct < 2; ++ct) {
                int ci = w * 32 + ct * 16 + lm;
                int q = cc0 + ci;
                float d2 = sr + sqc[ci] - 2.0f * acc[ct][v];
                float dd = (d2 > 0.f) ? sqrtf(d2) : 0.f;
                sum += ((labc[ci] == lr) && (q != p)) ? dd : 0.f;
            }
            #pragma unroll
            for (int off = 8; off; off >>= 1) sum += __shfl_xor(sum, off, 64);
            if (lm == 0) atomicAdd(&rs[ri], sum);
        }
    }
    __syncthreads();
    if (tid < 16 && rs[tid] != 0.f) atomicAdd(&meanpos[r0 + tid], rs[tid]);
}

// ---------------------------------------------------------------------------
// K3 (R13): 256x256 tile, 8 waves (2Mx4N, wave=128x64, acc 8x4), BK=64,
// NKT=8, double-buffered 128KB LDS, counted-vmcnt schedule (T3+T4):
//   per K-tile: read 24 frags of buf[cur] -> lgkmcnt(0)+s_barrier (reads in
//   regs, buffer free) -> issue 8 gl16 for tile kt+2 INTO buf[cur] ->
//   MFMA -> s_waitcnt vmcnt(8) (tile kt+1 landed; kt+2 still in flight) ->
//   s_barrier. Loads stay in flight ACROSS barriers (no vmcnt(0) drain in
//   the main loop). XOR-seg swizzle u = seg ^ (row&7) applied on BOTH sides
//   (pre-swizzled global source for linear gl16 write + swizzled ds_read).
// Grid: 528 triangular 256x256 blocks (= 8*66, bijective XCD swizzle).
// Epilogue: LDS-combined dual-side semi-hard mins, 1 global atomicMin per
// row/col per block.
// ---------------------------------------------------------------------------
#define NKT 8           // K-tiles of BK=64 over D=512
#define BUFH 32768      // ushorts per buffer: A 16384 | B 16384 (64 KB)

__global__ __launch_bounds__(512, 2) void k_minsh_mfma(
    const unsigned short* __restrict__ fh, const float* __restrict__ sqp,
    const int* __restrict__ labp, const float* __restrict__ meanpos,
    const float* __restrict__ pcinv, unsigned* __restrict__ minbits)
{
    // --- XCD swizzle (528 = 8*66, bijective) + triangular decode ---
    int t = (blockIdx.x & 7) * 66 + (blockIdx.x >> 3);
    int I = (int)((sqrtf(8.0f * (float)t + 1.0f) - 1.0f) * 0.5f);
    while ((I + 1) * (I + 2) / 2 <= t) ++I;
    while (I * (I + 1) / 2 > t) --I;
    const int J = t - I * (I + 1) / 2;
    const int i0 = I * 256, j0 = J * 256;

    __shared__ unsigned short LA[2][BUFH];                 // 128 KB
    __shared__ float s_mp2r[256], s_sqr[256], s_mp2c[256], s_sqc[256];
    __shared__ int s_labr[256], s_labc[256];

    const int tid = threadIdx.x;
    const int w = tid >> 6, L = tid & 63;
    const int lm = L & 15, ls = L >> 4;
    const int wm = w >> 2, wn = w & 3;          // 2M x 4N wave grid
    const int u0 = ls ^ (lm & 7);               // k-step 0 swizzled segment
    const int u1 = (4 + ls) ^ (lm & 7);         // k-step 1 swizzled segment

    // --- pre-swizzled staging sources: LDS[r][u] holds global seg u^(r&7) ---
    const unsigned short* srcA[4];
    const unsigned short* srcB[4];
    #pragma unroll
    for (int q = 0; q < 4; ++q) {
        int s = tid + 512 * q;                  // 16B slot 0..2047
        int r = s >> 3;                         // row 0..255
        int u = (s & 7) ^ (r & 7);              // global segment for this slot
        srcA[q] = fh + (size_t)(i0 + r) * D + u * 8;
        srcB[q] = fh + (size_t)(j0 + r) * D + u * 8;
    }

    #define K3_STAGE(kt_, b_) do {                                          \
        const int ko_ = (kt_) * 64;  /* ushort offset of K-chunk in a row */ \
        _Pragma("unroll")                                                   \
        for (int q = 0; q < 4; ++q)                                         \
            gl16(srcA[q] + ko_, &LA[(b_)][(w * 64 + 512 * q) * 8]);         \
        _Pragma("unroll")                                                   \
        for (int q = 0; q < 4; ++q)                                         \
            gl16(srcB[q] + ko_, &LA[(b_)][16384 + (w * 64 + 512 * q) * 8]); \
    } while (0)

    // --- metadata (each thread writes its own slots; visible after barriers)
    if (tid < 256) {
        int p = i0 + tid;
        float mp = meanpos[p] * pcinv[p];
        s_mp2r[tid] = mp * mp;
        s_sqr[tid]  = sqp[p];
        s_labr[tid] = labp[p];
    } else {
        int q = tid - 256, p = j0 + q;
        float mp = meanpos[p] * pcinv[p];
        s_mp2c[q] = mp * mp;
        s_sqc[q]  = sqp[p];
        s_labc[q] = labp[p];
    }

    float4v acc[8][4];
    #pragma unroll
    for (int mi = 0; mi < 8; ++mi)
        #pragma unroll
        for (int ni = 0; ni < 4; ++ni) acc[mi][ni] = (float4v){0.f, 0.f, 0.f, 0.f};

    // --- prologue: tiles 0 and 1 in flight; wait only tile 0 ---
    K3_STAGE(0, 0);
    __builtin_amdgcn_sched_barrier(0);          // keep tile0 loads older than tile1
    K3_STAGE(1, 1);
    asm volatile("s_waitcnt vmcnt(8)" ::: "memory");   // tile0 landed
    __builtin_amdgcn_sched_barrier(0);
    __builtin_amdgcn_s_barrier();
    __builtin_amdgcn_sched_barrier(0);

    const unsigned short* aB = &LA[0][(wm * 128 + lm) * 64];
    const unsigned short* bB = &LA[0][16384 + (wn * 64 + lm) * 64];

    for (int kt = 0; kt < NKT; ++kt) {
        const int co = (kt & 1) * BUFH;
        // ---- k-step 0: read 12 frags + 32 MFMA ----
        {
            short8 af[8], bf[4];
            #pragma unroll
            for (int mi = 0; mi < 8; ++mi)
                af[mi] = *(const short8*)(aB + co + mi * 1024 + u0 * 8);
            #pragma unroll
            for (int ni = 0; ni < 4; ++ni)
                bf[ni] = *(const short8*)(bB + co + ni * 1024 + u0 * 8);
            __builtin_amdgcn_s_setprio(1);
            #pragma unroll
            for (int ni = 0; ni < 4; ++ni)
                #pragma unroll
                for (int mi = 0; mi < 8; ++mi)
                    acc[mi][ni] = __builtin_amdgcn_mfma_f32_16x16x32_bf16(af[mi], bf[ni], acc[mi][ni], 0, 0, 0);
            __builtin_amdgcn_s_setprio(0);
        }
        // ---- k-step 1: read, fence, barrier, prefetch kt+2, MFMA ----
        {
            short8 af[8], bf[4];
            #pragma unroll
            for (int mi = 0; mi < 8; ++mi)
                af[mi] = *(const short8*)(aB + co + mi * 1024 + u1 * 8);
            #pragma unroll
            for (int ni = 0; ni < 4; ++ni)
                bf[ni] = *(const short8*)(bB + co + ni * 1024 + u1 * 8);
            asm volatile("s_waitcnt lgkmcnt(0)" ::: "memory");   // all buf[cur] reads in regs
            __builtin_amdgcn_sched_barrier(0);
            __builtin_amdgcn_s_barrier();                        // buffer free for overwrite
            __builtin_amdgcn_sched_barrier(0);
            if (kt + 2 < NKT) K3_STAGE(kt + 2, kt & 1);
            __builtin_amdgcn_s_setprio(1);
            #pragma unroll
            for (int ni = 0; ni < 4; ++ni)
                #pragma unroll
                for (int mi = 0; mi < 8; ++mi)
                    acc[mi][ni] = __builtin_amdgcn_mfma_f32_16x16x32_bf16(af[mi], bf[ni], acc[mi][ni], 0, 0, 0);
            __builtin_amdgcn_s_setprio(0);
        }
        if (kt + 1 < NKT) {
            if (kt + 2 < NKT) asm volatile("s_waitcnt vmcnt(8)" ::: "memory");
            else              asm volatile("s_waitcnt vmcnt(0)" ::: "memory");
            __builtin_amdgcn_sched_barrier(0);
            __builtin_amdgcn_s_barrier();                        // tile kt+1 visible to all
            __builtin_amdgcn_sched_barrier(0);
        }
    }
    #undef K3_STAGE

    // --- epilogue: dual-side semi-hard mins, LDS-combined ---
    // C/D: row = wm*128 + mi*16 + ls*4 + v, col = wn*64 + ni*16 + lm
    unsigned* rminb = (unsigned*)&LA[0][0];     // LA dead; reuse
    unsigned* cminb = rminb + 256;
    __syncthreads();
    if (tid < 256) rminb[tid] = INF_BITS;
    else           cminb[tid - 256] = INF_BITS;
    __syncthreads();

    const float INFF = __uint_as_float(INF_BITS);
    float sc[4], mp2c[4]; int lc[4];
    #pragma unroll
    for (int ni = 0; ni < 4; ++ni) {
        int cl = wn * 64 + ni * 16 + lm;
        sc[ni]   = s_sqc[cl];
        mp2c[ni] = s_mp2c[cl];
        lc[ni]   = s_labc[cl];
    }
    float vminc[4];
    #pragma unroll
    for (int ni = 0; ni < 4; ++ni) vminc[ni] = INFF;

    #pragma unroll
    for (int mi = 0; mi < 8; ++mi) {
        #pragma unroll
        for (int v = 0; v < 4; ++v) {
            int rl = wm * 128 + mi * 16 + ls * 4 + v;
            float mp2r = s_mp2r[rl];
            float sr   = s_sqr[rl];
            int   li   = s_labr[rl];
            float vminr = INFF;
            #pragma unroll
            for (int ni = 0; ni < 4; ++ni) {
                float d2 = fmaf(-2.0f, acc[mi][ni][v], sr + sc[ni]);
                bool neq = (li != lc[ni]);
                vminr     = fminf(vminr,     (neq && d2 > mp2r)     ? d2 : INFF);
                vminc[ni] = fminf(vminc[ni], (neq && d2 > mp2c[ni]) ? d2 : INFF);
            }
            #pragma unroll
            for (int off = 8; off; off >>= 1)
                vminr = fminf(vminr, __shfl_xor(vminr, off, 64));
            if (lm == 0 && __float_as_uint(vminr) != INF_BITS)
                atomicMin(&rminb[rl], __float_as_uint(vminr));
        }
    }
    #pragma unroll
    for (int ni = 0; ni < 4; ++ni) {
        float vc = vminc[ni];
        vc = fminf(vc, __shfl_xor(vc, 16, 64));
        vc = fminf(vc, __shfl_xor(vc, 32, 64));
        if (ls == 0 && __float_as_uint(vc) != INF_BITS)
            atomicMin(&cminb[wn * 64 + ni * 16 + lm], __float_as_uint(vc));
    }
    __syncthreads();
    if (tid < 256) {
        unsigned rb = rminb[tid];
        if (rb != INF_BITS) atomicMin(&minbits[i0 + tid], rb);
    } else if (i0 != j0) {
        unsigned cb = cminb[tid - 256];
        if (cb != INF_BITS) atomicMin(&minbits[j0 + tid - 256], cb);
    }
}

// ---------------------------------------------------------------------------
// K4: final reduction (unchanged).
// ---------------------------------------------------------------------------
__global__ __launch_bounds__(1024) void k_finish(const float* __restrict__ meanpos,
        const float* __restrict__ pcinv, const int* __restrict__ poscnt,
        const unsigned* __restrict__ minbits, float* __restrict__ out, int Bn) {
    float lsum = 0.f; int lcnt = 0;
    for (int i = threadIdx.x; i < Bn; i += 1024) {
        int pc = poscnt[i];
        bool valid = (pc > 1) && (pc < Bn);
        unsigned mb = minbits[i];
        if (valid && mb != INF_BITS) {
            float v = fmaf(meanpos[i], pcinv[i], MARGIN - sqrtf(__uint_as_float(mb)));
            lsum += (v > 0.f) ? v : 0.f;
            lcnt += 1;
        }
    }
    __shared__ float ssum[16]; __shared__ int scnt[16];
    int lane = threadIdx.x & 63, wid = threadIdx.x >> 6;
    #pragma unroll
    for (int off = 32; off; off >>= 1) {
        lsum += __shfl_down(lsum, off, 64);
        lcnt += __shfl_down(lcnt, off, 64);
    }
    if (lane == 0) { ssum[wid] = lsum; scnt[wid] = lcnt; }
    __syncthreads();
    if (threadIdx.x == 0) {
        float s = 0.f; int c = 0;
        #pragma unroll
        for (int q = 0; q < 16; ++q) { s += ssum[q]; c += scnt[q]; }
        out[0] = (c > 0) ? s / (float)c : 0.f;
    }
}

// ---------------------------------------------------------------------------
extern "C" void kernel_launch(void* const* d_in, const int* in_sizes, int n_in,
                              void* d_out, int out_size, void* d_ws, size_t ws_size,
                              hipStream_t stream) {
    const float* x = (const float*)d_in[0];
    const int* lab = (const int*)d_in[1];
    int Bn = in_sizes[1];                 // 8192; D fixed at 512

    size_t nd = (size_t)(Bn + PADR) * D;  // padded for banded over-read (K2)
    unsigned short* fh = (unsigned short*)d_ws;
    float* sqp        = (float*)(fh + nd);
    float* meanpos    = sqp + Bn;         // raw dist-sums
    float* pcinv      = meanpos + Bn;
    int* poscnt       = (int*)(pcinv + Bn);
    unsigned* minbits = (unsigned*)(poscnt + Bn);
    int* pos          = (int*)(minbits + Bn);
    int* labp         = pos + Bn;
    int* cstart_g     = labp + Bn;
    int* ccnt_g       = cstart_g + NCLS;

    k_bucket<<<1, 1024, 0, stream>>>(lab, Bn, pos, labp, cstart_g, ccnt_g,
                                     meanpos, pcinv, poscnt, minbits);
    k_normalize<<<Bn / 4, 256, 0, stream>>>(x, pos, fh, sqp);
    k_posband3<<<Bn / 16, 256, 0, stream>>>(fh, sqp, labp, cstart_g, ccnt_g,
                                            meanpos, Bn);
    int nbr = Bn / 256;                   // 32 row-tiles
    int T = nbr * (nbr + 1) / 2;          // 528 triangular 256x256 tiles
    k_minsh_mfma<<<T, 512, 0, stream>>>(fh, sqp, labp, meanpos, pcinv, minbits);
    k_finish<<<1, 1024, 0, stream>>>(meanpos, pcinv, poscnt, minbits,
                                     (float*)d_out, Bn);
}